// Round 10
// baseline (348.173 us; speedup 1.0000x reference)
//
#include <hip/hip_runtime.h>

// 2-layer LSTM (B=4096,T=512,D=16,H=50)+FC via single-wave MFMA.
// R16 = R15 (328us) + two zero-VALU cuts to the post-barrier LDS burst:
// (1) x read de-chained: stager lead 3->4 (STEPX(T) writes x[T+4] to slot
//     T&3); compute waves ds_read x[p+3] at phase p into alternating
//     bxA/bxB, consumed only at phase p+1's rx-prep -> the x read is pure
//     background LDS traffic, out of the critical post-barrier window.
// (2) kt=1 h-reads: kg==3 lanes (u56..63 = zero pad, A-frag zero there)
//     mirror kg==2's address (setup-time cndmask) -> LDS may broadcast-merge
//     duplicate addresses; SQ_LDS_BANK_CONFLICT will confirm.
// Math, layouts, barriers, rx pipelining, qv trees identical to R15.

#define TSTEPS 512
#define DIN 16
#define HID 50
#define BPB 16

typedef _Float16 half8 __attribute__((ext_vector_type(8)));
typedef _Float16 half4v __attribute__((ext_vector_type(4)));
typedef __fp16 fp16x2 __attribute__((ext_vector_type(2)));
typedef float f32x4 __attribute__((ext_vector_type(4)));
typedef float f32x2 __attribute__((ext_vector_type(2)));

#define MF(A, B, C) __builtin_amdgcn_mfma_f32_16x16x32_f16((A), (B), (C), 0, 0, 0)

// LDS: h double-buffered [2][16][144]; x 4-slot ring [4][16][80].
#define HBUF 2304
#define XBUF 1280
#define H0_O 0
#define H1_O 4608
#define X_O  9216
#define SH_BYTES (9216 + 4 * XBUF)   // 14336

// Barrier WITHOUT vmcnt drain: LDS ordering only (stager loads stay in flight).
#define BAR() asm volatile("s_waitcnt lgkmcnt(0)\ns_barrier" ::: "memory")

#define NL2E  (-1.4426950408889634f)   // -log2(e): scale for gates i,f,o
#define P2L2E (2.8853900817779268f)    // +2*log2(e): scale for gate g

__device__ __forceinline__ unsigned pack2h(float a, float b) {
  union { fp16x2 h; unsigned u; } pk;
  pk.h = __builtin_amdgcn_cvt_pkrtz(a, b);
  return pk.u;
}

// Pair-fused LSTM cell on PRE-SCALED gates (two independent cells A,B).
// g[0]=-L2E*i g[1]=-L2E*f g[2]=+2L2E*g g[3]=-L2E*o. C = 2L2E*c.
// Accuracy-verified R10/R12/R15 (absmax 4.88e-4). No eo clamp.
__device__ __forceinline__ f32x2 cell2p(const f32x4 gA, const f32x4 gB, f32x2& C) {
  f32x2 gi = {gA[0], gB[0]}, gf = {gA[1], gB[1]};
  f32x2 gg = {gA[2], gB[2]}, go = {gA[3], gB[3]};
  f32x2 ei, ef, eg, eo;
  ei[0] = __builtin_amdgcn_exp2f(gi[0]); ei[1] = __builtin_amdgcn_exp2f(gi[1]);
  ef[0] = __builtin_amdgcn_exp2f(gf[0]); ef[1] = __builtin_amdgcn_exp2f(gf[1]);
  eg[0] = __builtin_amdgcn_exp2f(gg[0]); eg[1] = __builtin_amdgcn_exp2f(gg[1]);
  eo[0] = __builtin_amdgcn_exp2f(go[0]); eo[1] = __builtin_amdgcn_exp2f(go[1]);
  const f32x2 one = {1.f, 1.f};
  const f32x2 c2 = {P2L2E, P2L2E};
  f32x2 a = one + ei, f = one + ef, b = one + eg;
  f32x2 ab = a * b;
  f32x2 f2 = ef * c2 + c2;                 // 2L2E * f
  f32x2 t = (eg - one) * f2 + C * ab;
  f32x2 p = f * ab;
  f32x2 rp;
  rp[0] = __builtin_amdgcn_rcpf(p[0]);
  rp[1] = __builtin_amdgcn_rcpf(p[1]);
  C = t * rp;
  f32x2 ec;
  ec[0] = __builtin_amdgcn_exp2f(fminf(C[0], 30.f));
  ec[1] = __builtin_amdgcn_exp2f(fminf(C[1], 30.f));
  f32x2 q = (one + eo) * (one + ec);
  float r2 = __builtin_amdgcn_rcpf(q[0] * q[1]);
  f32x2 h;
  h[0] = (ec[0] - 1.f) * (r2 * q[1]);
  h[1] = (ec[1] - 1.f) * (r2 * q[0]);
  return h;
}

// A-frag (fp16, 16x16x32): lane row g'=16gt+(lane&15)=4u+j, k-pos p=kt*32+(lane>>4)*8+i.
// permk: pos p holds source k = 8*(p>>3) + 4*(p&1) + ((p>>1)&3).
__device__ __forceinline__ half8 load_wfrag(const float* __restrict__ W, int kld,
                                            bool permk, int kreal, int gt, int kt,
                                            int lane, float scale) {
  const int gp = 16 * gt + (lane & 15);
  const int u = gp >> 2, j = gp & 3;
  const int kb = kt * 32 + (lane >> 4) * 8;
  half8 f;
#pragma unroll
  for (int i = 0; i < 8; ++i) {
    const int p = kb + i;
    const int kk = permk ? ((p & ~7) + (((p & 1) << 2) | ((p >> 1) & 3))) : p;
    float v = (u < HID && kk < kreal) ? W[(j * HID + u) * kld + kk] : 0.f;
    f[i] = (_Float16)(v * scale);
  }
  return f;
}

extern "C" __global__ void __launch_bounds__(512, 2)
lstm2_v16(const float* __restrict__ x,
          const float* __restrict__ Wih0, const float* __restrict__ Whh0,
          const float* __restrict__ bih0, const float* __restrict__ bhh0,
          const float* __restrict__ Wih1, const float* __restrict__ Whh1,
          const float* __restrict__ bih1, const float* __restrict__ bhh1,
          const float* __restrict__ Wfc, const float* __restrict__ bfc,
          float* __restrict__ out) {
  __shared__ __align__(16) char sh[SH_BYTES];
  const int tid = threadIdx.x;
  const int lane = tid & 63;
  const int wv = tid >> 6;
  const int bcol = lane & 15;
  const int kg = lane >> 4;
  const int bbase = blockIdx.x * BPB;
  const bool comp = (wv < 7);

  // x-staging mapping (wave 7): lane -> (batch row sbb, float-quad q)
  const int sbb = lane >> 2, q = lane & 3;
  const float* xrow = x + ((size_t)(bbase + sbb) * TSTEPS) * DIN + q * 4;

  for (int i = tid; i < SH_BYTES / 4; i += 512) ((int*)sh)[i] = 0;

  // ---- register-resident PRE-SCALED fp16 weight fragments + scaled f32 bias ----
  const float wsc = ((lane & 3) == 2) ? P2L2E : NL2E;
  half8 w0x[2], w0h[2][2], w1i[2][2], w1h[2][2];
  f32x4 bias0v[2] = {{0,0,0,0},{0,0,0,0}}, bias1v[2] = {{0,0,0,0},{0,0,0,0}};
  if (comp) {
#pragma unroll
    for (int gi = 0; gi < 2; ++gi) {
      const int gt = 2 * wv + gi;
      w0x[gi] = load_wfrag(Wih0, DIN, false, DIN, gt, 0, lane, wsc);
#pragma unroll
      for (int kt = 0; kt < 2; ++kt) {
        w0h[gi][kt] = load_wfrag(Whh0, HID, true, HID, gt, kt, lane, wsc);
        w1i[gi][kt] = load_wfrag(Wih1, HID, true, HID, gt, kt, lane, wsc);
        w1h[gi][kt] = load_wfrag(Whh1, HID, true, HID, gt, kt, lane, wsc);
      }
      const int u = 8 * wv + 4 * gi + kg;
      if (u < HID) {
#pragma unroll
        for (int j = 0; j < 4; ++j) {
          const float bs = (j == 2) ? P2L2E : NL2E;
          bias0v[gi][j] = bs * (bih0[j * HID + u] + bhh0[j * HID + u]);
          bias1v[gi][j] = bs * (bih1[j * HID + u] + bhh1[j * HID + u]);
        }
      }
    }
  }
  f32x2 C0 = {0.f, 0.f}, C1 = {0.f, 0.f};
  const int hoff = bcol * 144 + kg * 16;
  // kt=1 read offset: kg==3 lanes mirror kg==2 (their u-range 56..63 is zero
  // pad; A-frag is zero for k>=50 so B content is don't-care). Setup-time only.
  const int hoffB = bcol * 144 + ((kg == 3) ? 2 : kg) * 16;
  const int xoff = bcol * 80 + kg * 16;
  const int wo32 = bcol * 144 + wv * 16 + kg * 4;

  BAR();  // LDS zeroed

  // stage x[0..3] -> slots 0..3 (wave 7, direct; lead-4 ring)
  if (wv == 7) {
#pragma unroll
    for (int t = 0; t < 4; ++t) {
      float4 xq = *(const float4*)(xrow + (size_t)t * DIN);
      half4v h4;
#pragma unroll
      for (int i = 0; i < 4; ++i) h4[i] = (_Float16)((const float*)&xq)[i];
      *(half4v*)(sh + X_O + t * XBUF + sbb * 80 + q * 8) = h4;
    }
  }
  BAR();

  // prologue: h0[0] = cell(bias0 + Wih0 x[0]); pre-issue rx (x[1]); preload
  // bxB = x[2] for phase 0's rx-prep.
  float4 xrA, xrB;
  f32x4 rx0, rx1;
  half8 bxA, bxB;
  if (comp) {
    half8 bx0 = *(const half8*)(sh + X_O + 0 * XBUF + xoff);
    half8 bx1 = *(const half8*)(sh + X_O + 1 * XBUF + xoff);
    bxB = *(const half8*)(sh + X_O + 2 * XBUF + xoff);
    f32x4 a0 = MF(w0x[0], bx0, bias0v[0]);
    f32x4 a1 = MF(w0x[1], bx0, bias0v[1]);
    f32x2 H0 = cell2p(a0, a1, C0);
    *(unsigned*)(sh + H0_O + wo32) = pack2h(H0[0], H0[1]);
    rx0 = MF(w0x[0], bx1, bias0v[0]);   // x-part of phase 0's layer-0 gates
    rx1 = MF(w0x[1], bx1, bias0v[1]);
  } else if (wv == 7) {  // issue the register ring: x[4], x[5]
    xrA = *(const float4*)(xrow + (size_t)4 * DIN);
    xrB = *(const float4*)(xrow + (size_t)5 * DIN);
  }
  BAR();

// one compute step at parity P (reads h bufs P, writes P^1).
// rx0/rx1 = x-part prepared last phase. BXF <- ds_read x[p+3] (slot RSLOT,
// published >= start of this phase; consumed NEXT phase) -- dependency-free
// background LDS traffic. rx-prep at phase end uses BXU (= x[p+2], read
// last phase). qv = two 2-deep MFMA halves + add; rv = 2-deep on top of rx.
#define STEPCOMP(P, RSLOT, BXF, BXU)                                           \
  do {                                                                         \
    half8 bh0[2], bh1[2];                                                      \
    bh0[0] = *(const half8*)(sh + H0_O + (P)*HBUF + hoff);                     \
    bh1[0] = *(const half8*)(sh + H1_O + (P)*HBUF + hoff);                     \
    bh0[1] = *(const half8*)(sh + H0_O + (P)*HBUF + hoffB + 64);               \
    bh1[1] = *(const half8*)(sh + H1_O + (P)*HBUF + hoffB + 64);               \
    BXF = *(const half8*)(sh + X_O + (RSLOT)*XBUF + xoff);                     \
    const f32x4 z = {0.f, 0.f, 0.f, 0.f};                                      \
    f32x4 rv0 = MF(w0h[0][0], bh0[0], rx0);                                    \
    rv0 = MF(w0h[0][1], bh0[1], rv0);                                          \
    f32x4 rv1 = MF(w0h[1][0], bh0[0], rx1);                                    \
    rv1 = MF(w0h[1][1], bh0[1], rv1);                                          \
    f32x4 qa0 = MF(w1i[0][0], bh0[0], bias1v[0]);                              \
    qa0 = MF(w1h[0][0], bh1[0], qa0);                                          \
    f32x4 qb0 = MF(w1i[0][1], bh0[1], z);                                      \
    qb0 = MF(w1h[0][1], bh1[1], qb0);                                          \
    f32x4 qv0 = qa0 + qb0;                                                     \
    f32x4 qa1 = MF(w1i[1][0], bh0[0], bias1v[1]);                              \
    qa1 = MF(w1h[1][0], bh1[0], qa1);                                          \
    f32x4 qb1 = MF(w1i[1][1], bh0[1], z);                                      \
    qb1 = MF(w1h[1][1], bh1[1], qb1);                                          \
    f32x4 qv1 = qa1 + qb1;                                                     \
    f32x2 H0 = cell2p(rv0, rv1, C0);                                           \
    *(unsigned*)(sh + H0_O + ((P) ^ 1) * HBUF + wo32) = pack2h(H0[0], H0[1]);  \
    f32x2 H1 = cell2p(qv0, qv1, C1);                                           \
    *(unsigned*)(sh + H1_O + ((P) ^ 1) * HBUF + wo32) = pack2h(H1[0], H1[1]);  \
    rx0 = MF(w0x[0], BXU, bias0v[0]);                                          \
    rx1 = MF(w0x[1], BXU, bias0v[1]);                                          \
  } while (0)

// wave 7: ds-write XR (holds x[T+4]) into literal SLOT=T&3, load x[T+6].
#define STEPX(T, SLOT, XR)                                                     \
  do {                                                                         \
    half4v h4;                                                                 \
    _Pragma("unroll") for (int i = 0; i < 4; ++i)                              \
        h4[i] = (_Float16)((const float*)&(XR))[i];                            \
    *(half4v*)(sh + X_O + (SLOT)*XBUF + sbb * 80 + q * 8) = h4;                \
    int tl = (T) + 6;                                                          \
    if (tl > TSTEPS - 1) tl = TSTEPS - 1;                                      \
    (XR) = *(const float4*)(xrow + (size_t)tl * DIN);                          \
  } while (0)

  for (int s = 0; s < TSTEPS; s += 4) {
    // phase s   (P=0): rv<-rx(x[s+1]); read bxA<-slot3=x[s+3]; rx-prep<-bxB(x[s+2])
    if (comp) { STEPCOMP(0, 3, bxA, bxB); } else if (wv == 7) { STEPX(s, 0, xrA); }
    BAR();
    // phase s+1 (P=1): read bxB<-slot0=x[s+4]; rx-prep<-bxA(x[s+3])
    if (comp) { STEPCOMP(1, 0, bxB, bxA); } else if (wv == 7) { STEPX(s + 1, 1, xrB); }
    BAR();
    // phase s+2 (P=0): read bxA<-slot1=x[s+5]; rx-prep<-bxB(x[s+4])
    if (comp) { STEPCOMP(0, 1, bxA, bxB); } else if (wv == 7) { STEPX(s + 2, 2, xrA); }
    BAR();
    // phase s+3 (P=1): read bxB<-slot2=x[s+6]; rx-prep<-bxA(x[s+5])
    if (comp) { STEPCOMP(1, 2, bxB, bxA); } else if (wv == 7) { STEPX(s + 3, 3, xrB); }
    BAR();
  }

  // ---- FC epilogue: h1[511] in buf 0; read through pi-permutation ----
  if (tid < BPB) {
    float acc = bfc[0];
#pragma unroll 10
    for (int u = 0; u < HID; ++u) {
      const int pp = (u & ~7) + 2 * (u & 3) + ((u >> 2) & 1);
      float h = (float)(*(const _Float16*)(sh + H1_O + tid * 144 + pp * 2));
      acc = fmaf(Wfc[u], h, acc);
    }
    out[bbase + tid] = acc;
  }
}

extern "C" void kernel_launch(void* const* d_in, const int* in_sizes, int n_in,
                              void* d_out, int out_size, void* d_ws, size_t ws_size,
                              hipStream_t stream) {
  (void)in_sizes; (void)n_in; (void)d_ws; (void)ws_size; (void)out_size;
  lstm2_v16<<<dim3(4096 / BPB), dim3(512), 0, stream>>>(
      (const float*)d_in[0], (const float*)d_in[1], (const float*)d_in[2],
      (const float*)d_in[3], (const float*)d_in[4], (const float*)d_in[5],
      (const float*)d_in[6], (const float*)d_in[7], (const float*)d_in[8],
      (const float*)d_in[9], (const float*)d_in[10], (float*)d_out);
}

// Round 11
// 327.715 us; speedup vs baseline: 1.0624x; 1.0624x over previous
//
#include <hip/hip_runtime.h>

// 2-layer LSTM (B=4096,T=512,D=16,H=50)+FC via single-wave MFMA.
// R17 = R15 verbatim (session best: 328.0us) — revert of R16's regressing
// LDS-burst cuts. Final structure:
//  - 7 compute waves x 2 gate-tiles + 1 stager wave; 16 batches/block.
//  - fp16 MFMA 16x16x32, weights register-resident, PRE-SCALED into
//    exp2-domain (i,f,o rows by -log2e; g rows by +2log2e).
//  - x staged global->LDS 4-slot ring by wave 7; h double-buffered in LDS.
//  - x-MFMA (rx) software-pipelined across the barrier; qv = two 2-deep
//    MFMA trees + add; rv = 2-deep on top of rx.
//  - pair-fused cell2p: 10 exp2 + 3 rcp per 2 cells, f32x2-packed,
//    scaled cell state C = 2log2e*c; ec clamp 30; h via cvt_pkrtz.
// Evidence (R10-R16): phase floor ~940cyc is sync/latency-structural —
// invariant to waves/SIMD (1/2/3.5), LDS traffic (-24%), chain depth.

#define TSTEPS 512
#define DIN 16
#define HID 50
#define BPB 16

typedef _Float16 half8 __attribute__((ext_vector_type(8)));
typedef _Float16 half4v __attribute__((ext_vector_type(4)));
typedef __fp16 fp16x2 __attribute__((ext_vector_type(2)));
typedef float f32x4 __attribute__((ext_vector_type(4)));
typedef float f32x2 __attribute__((ext_vector_type(2)));

#define MF(A, B, C) __builtin_amdgcn_mfma_f32_16x16x32_f16((A), (B), (C), 0, 0, 0)

// LDS: h double-buffered [2][16][144]; x 4-slot ring [4][16][80].
#define HBUF 2304
#define XBUF 1280
#define H0_O 0
#define H1_O 4608
#define X_O  9216
#define SH_BYTES (9216 + 4 * XBUF)   // 14336

// Barrier WITHOUT vmcnt drain: LDS ordering only (stager loads stay in flight).
#define BAR() asm volatile("s_waitcnt lgkmcnt(0)\ns_barrier" ::: "memory")

#define NL2E  (-1.4426950408889634f)   // -log2(e): scale for gates i,f,o
#define P2L2E (2.8853900817779268f)    // +2*log2(e): scale for gate g

__device__ __forceinline__ unsigned pack2h(float a, float b) {
  union { fp16x2 h; unsigned u; } pk;
  pk.h = __builtin_amdgcn_cvt_pkrtz(a, b);
  return pk.u;
}

// Pair-fused LSTM cell on PRE-SCALED gates (two independent cells A,B).
// g[0]=-L2E*i g[1]=-L2E*f g[2]=+2L2E*g g[3]=-L2E*o. C = 2L2E*c.
// Accuracy-verified R10/R12/R15 (absmax 4.88e-4). No eo clamp.
__device__ __forceinline__ f32x2 cell2p(const f32x4 gA, const f32x4 gB, f32x2& C) {
  f32x2 gi = {gA[0], gB[0]}, gf = {gA[1], gB[1]};
  f32x2 gg = {gA[2], gB[2]}, go = {gA[3], gB[3]};
  f32x2 ei, ef, eg, eo;
  ei[0] = __builtin_amdgcn_exp2f(gi[0]); ei[1] = __builtin_amdgcn_exp2f(gi[1]);
  ef[0] = __builtin_amdgcn_exp2f(gf[0]); ef[1] = __builtin_amdgcn_exp2f(gf[1]);
  eg[0] = __builtin_amdgcn_exp2f(gg[0]); eg[1] = __builtin_amdgcn_exp2f(gg[1]);
  eo[0] = __builtin_amdgcn_exp2f(go[0]); eo[1] = __builtin_amdgcn_exp2f(go[1]);
  const f32x2 one = {1.f, 1.f};
  const f32x2 c2 = {P2L2E, P2L2E};
  f32x2 a = one + ei, f = one + ef, b = one + eg;
  f32x2 ab = a * b;
  f32x2 f2 = ef * c2 + c2;                 // 2L2E * f
  f32x2 t = (eg - one) * f2 + C * ab;
  f32x2 p = f * ab;
  f32x2 rp;
  rp[0] = __builtin_amdgcn_rcpf(p[0]);
  rp[1] = __builtin_amdgcn_rcpf(p[1]);
  C = t * rp;
  f32x2 ec;
  ec[0] = __builtin_amdgcn_exp2f(fminf(C[0], 30.f));
  ec[1] = __builtin_amdgcn_exp2f(fminf(C[1], 30.f));
  f32x2 q = (one + eo) * (one + ec);
  float r2 = __builtin_amdgcn_rcpf(q[0] * q[1]);
  f32x2 h;
  h[0] = (ec[0] - 1.f) * (r2 * q[1]);
  h[1] = (ec[1] - 1.f) * (r2 * q[0]);
  return h;
}

// A-frag (fp16, 16x16x32): lane row g'=16gt+(lane&15)=4u+j, k-pos p=kt*32+(lane>>4)*8+i.
// permk: pos p holds source k = 8*(p>>3) + 4*(p&1) + ((p>>1)&3).
__device__ __forceinline__ half8 load_wfrag(const float* __restrict__ W, int kld,
                                            bool permk, int kreal, int gt, int kt,
                                            int lane, float scale) {
  const int gp = 16 * gt + (lane & 15);
  const int u = gp >> 2, j = gp & 3;
  const int kb = kt * 32 + (lane >> 4) * 8;
  half8 f;
#pragma unroll
  for (int i = 0; i < 8; ++i) {
    const int p = kb + i;
    const int kk = permk ? ((p & ~7) + (((p & 1) << 2) | ((p >> 1) & 3))) : p;
    float v = (u < HID && kk < kreal) ? W[(j * HID + u) * kld + kk] : 0.f;
    f[i] = (_Float16)(v * scale);
  }
  return f;
}

extern "C" __global__ void __launch_bounds__(512, 2)
lstm2_v17(const float* __restrict__ x,
          const float* __restrict__ Wih0, const float* __restrict__ Whh0,
          const float* __restrict__ bih0, const float* __restrict__ bhh0,
          const float* __restrict__ Wih1, const float* __restrict__ Whh1,
          const float* __restrict__ bih1, const float* __restrict__ bhh1,
          const float* __restrict__ Wfc, const float* __restrict__ bfc,
          float* __restrict__ out) {
  __shared__ __align__(16) char sh[SH_BYTES];
  const int tid = threadIdx.x;
  const int lane = tid & 63;
  const int wv = tid >> 6;
  const int bcol = lane & 15;
  const int kg = lane >> 4;
  const int bbase = blockIdx.x * BPB;
  const bool comp = (wv < 7);

  // x-staging mapping (wave 7): lane -> (batch row sbb, float-quad q)
  const int sbb = lane >> 2, q = lane & 3;
  const float* xrow = x + ((size_t)(bbase + sbb) * TSTEPS) * DIN + q * 4;

  for (int i = tid; i < SH_BYTES / 4; i += 512) ((int*)sh)[i] = 0;

  // ---- register-resident PRE-SCALED fp16 weight fragments + scaled f32 bias ----
  const float wsc = ((lane & 3) == 2) ? P2L2E : NL2E;
  half8 w0x[2], w0h[2][2], w1i[2][2], w1h[2][2];
  f32x4 bias0v[2] = {{0,0,0,0},{0,0,0,0}}, bias1v[2] = {{0,0,0,0},{0,0,0,0}};
  if (comp) {
#pragma unroll
    for (int gi = 0; gi < 2; ++gi) {
      const int gt = 2 * wv + gi;
      w0x[gi] = load_wfrag(Wih0, DIN, false, DIN, gt, 0, lane, wsc);
#pragma unroll
      for (int kt = 0; kt < 2; ++kt) {
        w0h[gi][kt] = load_wfrag(Whh0, HID, true, HID, gt, kt, lane, wsc);
        w1i[gi][kt] = load_wfrag(Wih1, HID, true, HID, gt, kt, lane, wsc);
        w1h[gi][kt] = load_wfrag(Whh1, HID, true, HID, gt, kt, lane, wsc);
      }
      const int u = 8 * wv + 4 * gi + kg;
      if (u < HID) {
#pragma unroll
        for (int j = 0; j < 4; ++j) {
          const float bs = (j == 2) ? P2L2E : NL2E;
          bias0v[gi][j] = bs * (bih0[j * HID + u] + bhh0[j * HID + u]);
          bias1v[gi][j] = bs * (bih1[j * HID + u] + bhh1[j * HID + u]);
        }
      }
    }
  }
  f32x2 C0 = {0.f, 0.f}, C1 = {0.f, 0.f};
  const int hoff = bcol * 144 + kg * 16;
  const int xoff = bcol * 80 + kg * 16;
  const int wo32 = bcol * 144 + wv * 16 + kg * 4;

  BAR();  // LDS zeroed

  // stage x[0..2] -> slots 0..2 (wave 7, direct)
  if (wv == 7) {
#pragma unroll
    for (int t = 0; t < 3; ++t) {
      float4 xq = *(const float4*)(xrow + (size_t)t * DIN);
      half4v h4;
#pragma unroll
      for (int i = 0; i < 4; ++i) h4[i] = (_Float16)((const float*)&xq)[i];
      *(half4v*)(sh + X_O + t * XBUF + sbb * 80 + q * 8) = h4;
    }
  }
  BAR();

  // prologue: h0[0] = cell(bias0 + Wih0 x[0]) -> h0 buf 0; pre-issue rx for
  // phase 0 (x[1]).
  float4 xrA, xrB;
  f32x4 rx0, rx1;
  if (comp) {
    half8 bx0 = *(const half8*)(sh + X_O + 0 * XBUF + xoff);
    half8 bx1 = *(const half8*)(sh + X_O + 1 * XBUF + xoff);
    f32x4 a0 = MF(w0x[0], bx0, bias0v[0]);
    f32x4 a1 = MF(w0x[1], bx0, bias0v[1]);
    f32x2 H0 = cell2p(a0, a1, C0);
    *(unsigned*)(sh + H0_O + wo32) = pack2h(H0[0], H0[1]);
    rx0 = MF(w0x[0], bx1, bias0v[0]);   // x-part of phase 0's layer-0 gates
    rx1 = MF(w0x[1], bx1, bias0v[1]);
  } else if (wv == 7) {  // issue the register ring: x[3], x[4]
    xrA = *(const float4*)(xrow + (size_t)3 * DIN);
    xrB = *(const float4*)(xrow + (size_t)4 * DIN);
  }
  BAR();

// one compute step at compile-time h-parity P (reads h bufs P, writes P^1).
// rx0/rx1 hold the x-part (computed last phase, pipelined across the barrier);
// this phase reads x[t+2] from ring slot XSN and issues next phase's rx at
// the end. qv = two 2-deep MFMA halves + add; rv = 2-deep on top of rx.
#define STEPCOMP(P, XSN)                                                       \
  do {                                                                         \
    half8 bh0[2], bh1[2];                                                      \
    _Pragma("unroll") for (int kt = 0; kt < 2; ++kt) {                         \
      bh0[kt] = *(const half8*)(sh + H0_O + (P)*HBUF + hoff + kt * 64);        \
      bh1[kt] = *(const half8*)(sh + H1_O + (P)*HBUF + hoff + kt * 64);        \
    }                                                                          \
    half8 bxn = *(const half8*)(sh + X_O + (XSN)*XBUF + xoff);                 \
    const f32x4 z = {0.f, 0.f, 0.f, 0.f};                                      \
    f32x4 rv0 = MF(w0h[0][0], bh0[0], rx0);                                    \
    rv0 = MF(w0h[0][1], bh0[1], rv0);                                          \
    f32x4 rv1 = MF(w0h[1][0], bh0[0], rx1);                                    \
    rv1 = MF(w0h[1][1], bh0[1], rv1);                                          \
    f32x4 qa0 = MF(w1i[0][0], bh0[0], bias1v[0]);                              \
    qa0 = MF(w1h[0][0], bh1[0], qa0);                                          \
    f32x4 qb0 = MF(w1i[0][1], bh0[1], z);                                      \
    qb0 = MF(w1h[0][1], bh1[1], qb0);                                          \
    f32x4 qv0 = qa0 + qb0;                                                     \
    f32x4 qa1 = MF(w1i[1][0], bh0[0], bias1v[1]);                              \
    qa1 = MF(w1h[1][0], bh1[0], qa1);                                          \
    f32x4 qb1 = MF(w1i[1][1], bh0[1], z);                                      \
    qb1 = MF(w1h[1][1], bh1[1], qb1);                                          \
    f32x4 qv1 = qa1 + qb1;                                                     \
    f32x2 H0 = cell2p(rv0, rv1, C0);                                           \
    *(unsigned*)(sh + H0_O + ((P) ^ 1) * HBUF + wo32) = pack2h(H0[0], H0[1]);  \
    f32x2 H1 = cell2p(qv0, qv1, C1);                                           \
    *(unsigned*)(sh + H1_O + ((P) ^ 1) * HBUF + wo32) = pack2h(H1[0], H1[1]);  \
    rx0 = MF(w0x[0], bxn, bias0v[0]);                                          \
    rx1 = MF(w0x[1], bxn, bias0v[1]);                                          \
  } while (0)

// wave 7: ds-write XR (holds x[t+3]) into literal SLOT=(t+3)&3, load x[t+5].
#define STEPX(T, SLOT, XR)                                                     \
  do {                                                                         \
    half4v h4;                                                                 \
    _Pragma("unroll") for (int i = 0; i < 4; ++i)                              \
        h4[i] = (_Float16)((const float*)&(XR))[i];                            \
    *(half4v*)(sh + X_O + (SLOT)*XBUF + sbb * 80 + q * 8) = h4;                \
    int tl = (T) + 5;                                                          \
    if (tl > TSTEPS - 1) tl = TSTEPS - 1;                                      \
    (XR) = *(const float4*)(xrow + (size_t)tl * DIN);                          \
  } while (0)

  for (int s = 0; s < TSTEPS; s += 4) {
    // phase s   (P=0): rv from rx (=x[s+1]); reads slot 2 = x[s+2] for next rx
    if (comp) { STEPCOMP(0, 2); } else if (wv == 7) { STEPX(s, 3, xrA); }
    BAR();
    // phase s+1 (P=1): reads slot 3 = x[s+3]
    if (comp) { STEPCOMP(1, 3); } else if (wv == 7) { STEPX(s + 1, 0, xrB); }
    BAR();
    // phase s+2 (P=0): reads slot 0 = x[s+4]
    if (comp) { STEPCOMP(0, 0); } else if (wv == 7) { STEPX(s + 2, 1, xrA); }
    BAR();
    // phase s+3 (P=1): reads slot 1 = x[s+5]
    if (comp) { STEPCOMP(1, 1); } else if (wv == 7) { STEPX(s + 3, 2, xrB); }
    BAR();
  }

  // ---- FC epilogue: h1[511] in buf 0; read through pi-permutation ----
  if (tid < BPB) {
    float acc = bfc[0];
#pragma unroll 10
    for (int u = 0; u < HID; ++u) {
      const int pp = (u & ~7) + 2 * (u & 3) + ((u >> 2) & 1);
      float h = (float)(*(const _Float16*)(sh + H1_O + tid * 144 + pp * 2));
      acc = fmaf(Wfc[u], h, acc);
    }
    out[bbase + tid] = acc;
  }
}

extern "C" void kernel_launch(void* const* d_in, const int* in_sizes, int n_in,
                              void* d_out, int out_size, void* d_ws, size_t ws_size,
                              hipStream_t stream) {
  (void)in_sizes; (void)n_in; (void)d_ws; (void)ws_size; (void)out_size;
  lstm2_v17<<<dim3(4096 / BPB), dim3(512), 0, stream>>>(
      (const float*)d_in[0], (const float*)d_in[1], (const float*)d_in[2],
      (const float*)d_in[3], (const float*)d_in[4], (const float*)d_in[5],
      (const float*)d_in[6], (const float*)d_in[7], (const float*)d_in[8],
      (const float*)d_in[9], (const float*)d_in[10], (float*)d_out);
}